// Round 1
// baseline (244.586 us; speedup 1.0000x reference)
//
#include <hip/hip_runtime.h>
#include <math.h>

// Problem dims (from reference setup_inputs): img (8, 3, 1024, 2048) fp32.
#define BC 24          // B*C planes
#define H 1024
#define W 2048
#define OH 32          // output tile height
#define OW 64          // output tile width
#define NTHREADS 256

// Constants exactly as JAX float32 weak-type conversion of the Python doubles.
__device__ __forceinline__ float masked_grad1(float g1, float g2, float g3) {
    const float HALF_T     = (float)(0.5 / 1023.0);
    const float GRD_BOTTOM = (float)(1.0 / 1023.0);
    const float GRD_UP     = (float)(4.0 / 1023.0);
    const float THIRD      = (float)(1.0 / 3.0);
    float m = (g1 + g2 + g3) * THIRD;
    float g = (g1 < m - HALF_T || g1 > m + HALF_T) ? 0.0f : g1;
    float ag = fabsf(g);
    if (ag < GRD_BOTTOM || ag > GRD_UP) g = 0.0f;
    return g;
}

__global__ __launch_bounds__(NTHREADS) void gradmap_closing_kernel(
        const float* __restrict__ img, float* __restrict__ out) {
    const int tileX = blockIdx.x;          // 0..W/OW-1
    const int tileY = blockIdx.y;          // 0..H/OH-1
    const int plane = blockIdx.z;          // 0..BC-1
    const int ox0 = tileX * OW;
    const int oy0 = tileY * OH;
    const float* __restrict__ ip = img + (size_t)plane * H * W;
    float* __restrict__ op = out + (size_t)plane * H * W;

    // LDS tiles
    __shared__ float simg[OH + 10][OW + 10];   // img with ±5 halo (zero-padded at image border)
    __shared__ float sgrad[OH + 4][OW + 4];    // gradmap with ±2 halo (-inf outside image)
    __shared__ float smax[OH + 2][OW + 2];     // dilation with ±1 halo (+inf outside image)

    const int tid = threadIdx.x;

    // ---- Phase 1: stage img tile + halo into LDS (zero pad = _dshift semantics) ----
    #pragma unroll 1
    for (int i = tid; i < (OH + 10) * (OW + 10); i += NTHREADS) {
        int r = i / (OW + 10);
        int c = i - r * (OW + 10);
        int gy = oy0 - 5 + r;
        int gx = ox0 - 5 + c;
        float v = 0.0f;
        if (gy >= 0 && gy < H && gx >= 0 && gx < W) v = ip[gy * W + gx];
        simg[r][c] = v;
    }
    __syncthreads();

    // ---- Phase 2: gradmap tile with ±2 halo; -inf marks outside-image ----
    const float INV_GRD_UP = 255.75f;  // 1023/4 exact
    #pragma unroll 1
    for (int i = tid; i < (OH + 4) * (OW + 4); i += NTHREADS) {
        int r = i / (OW + 4);
        int c = i - r * (OW + 4);
        int gy = oy0 - 2 + r;
        int gx = ox0 - 2 + c;
        float v;
        if (gy < 0 || gy >= H || gx < 0 || gx >= W) {
            v = -INFINITY;
        } else {
            int rr = r + 3, cc = c + 3;  // position in simg
            // x-direction gradients
            float g1 = simg[rr][cc + 1] - simg[rr][cc - 1];
            float g2 = simg[rr][cc + 2] - simg[rr][cc - 2];
            float g3 = simg[rr][cc + 3] - simg[rr][cc - 3];
            float gxv = masked_grad1(g1, g2, g3);
            // y-direction gradients
            g1 = simg[rr + 1][cc] - simg[rr - 1][cc];
            g2 = simg[rr + 2][cc] - simg[rr - 2][cc];
            g3 = simg[rr + 3][cc] - simg[rr - 3][cc];
            float gyv = masked_grad1(g1, g2, g3);
            v = fmaxf(fabsf(gxv), fabsf(gyv)) * INV_GRD_UP;
        }
        sgrad[r][c] = v;
    }
    __syncthreads();

    // ---- Phase 3: 3x3 dilation (max) with ±1 halo; +inf marks outside-image ----
    #pragma unroll 1
    for (int i = tid; i < (OH + 2) * (OW + 2); i += NTHREADS) {
        int r = i / (OW + 2);
        int c = i - r * (OW + 2);
        int gy = oy0 - 1 + r;
        int gx = ox0 - 1 + c;
        float v;
        if (gy < 0 || gy >= H || gx < 0 || gx >= W) {
            v = INFINITY;   // erosion ignores these
        } else {
            v = -INFINITY;  // dilation ignores out-of-image gradmap entries (-inf)
            #pragma unroll
            for (int dy = 0; dy < 3; ++dy)
                #pragma unroll
                for (int dx = 0; dx < 3; ++dx)
                    v = fmaxf(v, sgrad[r + dy][c + dx]);
        }
        smax[r][c] = v;
    }
    __syncthreads();

    // ---- Phase 4: 3x3 erosion (min), write output ----
    #pragma unroll 1
    for (int i = tid; i < OH * OW; i += NTHREADS) {
        int r = i >> 6;        // OW == 64
        int c = i & (OW - 1);
        float v = INFINITY;
        #pragma unroll
        for (int dy = 0; dy < 3; ++dy)
            #pragma unroll
            for (int dx = 0; dx < 3; ++dx)
                v = fminf(v, smax[r + dy][c + dx]);
        op[(size_t)(oy0 + r) * W + (ox0 + c)] = v;
    }
}

extern "C" void kernel_launch(void* const* d_in, const int* in_sizes, int n_in,
                              void* d_out, int out_size, void* d_ws, size_t ws_size,
                              hipStream_t stream) {
    const float* img = (const float*)d_in[0];
    float* out = (float*)d_out;
    dim3 grid(W / OW, H / OH, BC);   // 32 x 32 x 24
    dim3 block(NTHREADS);
    gradmap_closing_kernel<<<grid, block, 0, stream>>>(img, out);
}

// Round 2
// 105.559 us; speedup vs baseline: 2.3171x; 2.3171x over previous
//
#include <hip/hip_runtime.h>
#include <math.h>

// img (8, 3, 1024, 2048) fp32 -> same-shape fp32 output.
#define Wd 2048
#define Hd 1024
#define BC 24
#define CH 32          // output rows per block
#define NT 512         // threads/block; each owns 4 consecutive columns

__device__ __forceinline__ float masked_grad1(float g1, float g2, float g3) {
    const float HALF_T     = (float)(0.5 / 1023.0);
    const float GRD_BOTTOM = (float)(1.0 / 1023.0);
    const float GRD_UP     = (float)(4.0 / 1023.0);
    const float THIRD      = (float)(1.0 / 3.0);
    float m = (g1 + g2 + g3) * THIRD;
    float g = (g1 < m - HALF_T || g1 > m + HALF_T) ? 0.0f : g1;
    float ag = fabsf(g);
    if (ag < GRD_BOTTOM || ag > GRD_UP) g = 0.0f;
    return g;
}

__device__ __forceinline__ float4 f4(float v) { return make_float4(v, v, v, v); }

__global__ __launch_bounds__(NT) void gradmap_sweep_kernel(
        const float* __restrict__ img, float* __restrict__ out) {
    const int plane = blockIdx.y;          // 0..23
    const int y0 = blockIdx.x * CH;        // chunk start row
    const int tid = threadIdx.x;
    const int c0 = tid << 2;               // first owned column
    const float* __restrict__ ip = img + (size_t)plane * Hd * Wd;
    float* __restrict__ op = out + (size_t)plane * Hd * Wd;

    // LDS: img ring (4 rows, x-halo ±5 -> col c stored at +8),
    //      grad row (halo ±1 -> col c at +4), vmax row (halo ±1 -> col c at +2)
    __shared__ float s_img[4][Wd + 16];
    __shared__ float s_grad[Wd + 8];
    __shared__ float s_vmax[Wd + 4];

    // constant halos (written once; in-loop stores never touch them)
    if (tid < 8) {
        #pragma unroll
        for (int r = 0; r < 4; ++r) {
            s_img[r][tid] = 0.0f;            // cols -8..-1 region (zero pad)
            s_img[r][Wd + 8 + tid] = 0.0f;   // cols W..W+7
        }
    }
    if (tid == 8) {
        s_grad[3]      = -INFINITY;  // grad col -1  (dilation identity)
        s_grad[4 + Wd] = -INFINITY;  // grad col W
        s_vmax[1]      =  INFINITY;  // vmax col -1  (erosion identity)
        s_vmax[2 + Wd] =  INFINITY;  // vmax col W
    }

    const float INV_GRD_UP = 255.75f;  // 1023/4 exact

    // img register ring: im0 = row L (newest) ... im6 = row L-6 (own 4 cols)
    float4 im0 = f4(0.f), im1 = f4(0.f), im2 = f4(0.f), im3 = f4(0.f),
           im4 = f4(0.f), im5 = f4(0.f), im6 = f4(0.f);
    // hmax ring (rows L-5, L-4), hmin ring (rows L-6, L-5)
    float4 h0 = f4(-INFINITY), h1 = f4(-INFINITY);
    float4 n0 = f4(INFINITY),  n1 = f4(INFINITY);

    // ---- prime: rows y0-6 .. y0 ----
    #pragma unroll
    for (int r = 0; r < 7; ++r) {
        int L = y0 - 6 + r;
        float4 v = f4(0.f);
        if (L >= 0) v = *(const float4*)(ip + (size_t)L * Wd + c0);
        im6 = im5; im5 = im4; im4 = im3; im3 = im2; im2 = im1; im1 = im0; im0 = v;
        *(float4*)&s_img[L & 3][c0 + 8] = v;
    }
    // prefetch row y0+1
    float4 vpref = f4(0.f);
    {
        int Lp = y0 + 1;
        if (Lp < Hd) vpref = *(const float4*)(ip + (size_t)Lp * Wd + c0);
    }
    __syncthreads();

    // ---- main sweep: L = y0+1 .. y0+CH+4 ----
    #pragma unroll 4
    for (int L = y0 + 1; L <= y0 + CH + 4; ++L) {
        // consume prefetched row L; write to LDS ring; shift register ring
        float4 v = vpref;
        im6 = im5; im5 = im4; im4 = im3; im3 = im2; im2 = im1; im1 = im0; im0 = v;
        *(float4*)&s_img[L & 3][c0 + 8] = v;
        // issue prefetch for row L+1 (used next iteration -> latency hidden)
        vpref = f4(0.f);
        if (L + 1 < Hd) vpref = *(const float4*)(ip + (size_t)(L + 1) * Wd + c0);

        // ---- grad row L-3 ----
        const float* sr = s_img[(L - 3) & 3];
        float4 lf = *(const float4*)&sr[c0 + 8 - 4];  // cols c0-4..c0-1
        float4 rt = *(const float4*)&sr[c0 + 8 + 4];  // cols c0+4..c0+7
        float4 ce = im3;                              // own cols, row L-3
        float4 gradv;
        {
            // x-direction
            float gx0 = masked_grad1(ce.y - lf.w, ce.z - lf.z, ce.w - lf.y);
            float gx1 = masked_grad1(ce.z - ce.x, ce.w - lf.w, rt.x - lf.z);
            float gx2 = masked_grad1(ce.w - ce.y, rt.x - ce.x, rt.y - lf.w);
            float gx3 = masked_grad1(rt.x - ce.z, rt.y - ce.y, rt.z - ce.x);
            // y-direction: rows L-2/L-4 (g1), L-1/L-5 (g2), L/L-6 (g3)
            float gy0 = masked_grad1(im2.x - im4.x, im1.x - im5.x, im0.x - im6.x);
            float gy1 = masked_grad1(im2.y - im4.y, im1.y - im5.y, im0.y - im6.y);
            float gy2 = masked_grad1(im2.z - im4.z, im1.z - im5.z, im0.z - im6.z);
            float gy3 = masked_grad1(im2.w - im4.w, im1.w - im5.w, im0.w - im6.w);
            gradv.x = fmaxf(fabsf(gx0), fabsf(gy0)) * INV_GRD_UP;
            gradv.y = fmaxf(fabsf(gx1), fabsf(gy1)) * INV_GRD_UP;
            gradv.z = fmaxf(fabsf(gx2), fabsf(gy2)) * INV_GRD_UP;
            gradv.w = fmaxf(fabsf(gx3), fabsf(gy3)) * INV_GRD_UP;
        }
        *(float4*)&s_grad[c0 + 4] = gradv;
        __syncthreads();  // B1: grad row visible

        // ---- hmax row L-3, vmax row L-4 ----
        float gl = s_grad[c0 + 3];  // col c0-1
        float gr = s_grad[c0 + 8];  // col c0+4
        float4 hm_new;
        hm_new.x = fmaxf(fmaxf(gl, gradv.x), gradv.y);
        hm_new.y = fmaxf(fmaxf(gradv.x, gradv.y), gradv.z);
        hm_new.z = fmaxf(fmaxf(gradv.y, gradv.z), gradv.w);
        hm_new.w = fmaxf(fmaxf(gradv.z, gradv.w), gr);
        if ((unsigned)(L - 3) >= (unsigned)Hd) hm_new = f4(-INFINITY);

        float4 vm;
        vm.x = fmaxf(fmaxf(h0.x, h1.x), hm_new.x);
        vm.y = fmaxf(fmaxf(h0.y, h1.y), hm_new.y);
        vm.z = fmaxf(fmaxf(h0.z, h1.z), hm_new.z);
        vm.w = fmaxf(fmaxf(h0.w, h1.w), hm_new.w);
        if ((unsigned)(L - 4) >= (unsigned)Hd) vm = f4(INFINITY);

        *(float4*)&s_vmax[c0 + 2] = vm;
        __syncthreads();  // B2: vmax row visible

        // ---- hmin row L-4, out row L-5 ----
        float vl = s_vmax[c0 + 1];  // col c0-1
        float vr = s_vmax[c0 + 6];  // col c0+4
        float4 hn_new;
        hn_new.x = fminf(fminf(vl, vm.x), vm.y);
        hn_new.y = fminf(fminf(vm.x, vm.y), vm.z);
        hn_new.z = fminf(fminf(vm.y, vm.z), vm.w);
        hn_new.w = fminf(fminf(vm.z, vm.w), vr);

        int o_row = L - 5;
        if (o_row >= y0 && o_row < y0 + CH) {
            float4 o;
            o.x = fminf(fminf(n0.x, n1.x), hn_new.x);
            o.y = fminf(fminf(n0.y, n1.y), hn_new.y);
            o.z = fminf(fminf(n0.z, n1.z), hn_new.z);
            o.w = fminf(fminf(n0.w, n1.w), hn_new.w);
            *(float4*)(op + (size_t)o_row * Wd + c0) = o;
        }

        h0 = h1; h1 = hm_new;
        n0 = n1; n1 = hn_new;
    }
}

extern "C" void kernel_launch(void* const* d_in, const int* in_sizes, int n_in,
                              void* d_out, int out_size, void* d_ws, size_t ws_size,
                              hipStream_t stream) {
    const float* img = (const float*)d_in[0];
    float* out = (float*)d_out;
    dim3 grid(Hd / CH, BC);   // 32 x 24 = 768 blocks = 3/CU balanced
    dim3 block(NT);
    gradmap_sweep_kernel<<<grid, block, 0, stream>>>(img, out);
}